// Round 12
// baseline (24251.788 us; speedup 1.0000x reference)
//
#include <hip/hip_runtime.h>

typedef _Float16 f16;
typedef _Float16 f16x4 __attribute__((ext_vector_type(4)));
typedef _Float16 f16x8 __attribute__((ext_vector_type(8)));
typedef float f32x4 __attribute__((ext_vector_type(4)));

#define NB 32
#define NT 256
#define NE 256
#define NU 1024
#define NV 128

#define MEMF() asm volatile("" ::: "memory")

template<bool B> struct BoolT { static constexpr bool value = B; };

// ---------- agent-coherent (cross-XCD, L3-level) helpers ----------
__device__ __forceinline__ unsigned long long cload64(const f16* p) {
    return __hip_atomic_load((const unsigned long long*)p, __ATOMIC_RELAXED,
                             __HIP_MEMORY_SCOPE_AGENT);
}
__device__ __forceinline__ float cloadf(const float* p) {
    return __hip_atomic_load(p, __ATOMIC_RELAXED, __HIP_MEMORY_SCOPE_AGENT);
}

// ---------- dual-publish stores: plain (same-XCD L2) + agent (L3) ----------
__device__ __forceinline__ void dst16(f16* p, f16 v) {
    unsigned short b = __builtin_bit_cast(unsigned short, v);
    __hip_atomic_store((unsigned short*)p, b, __ATOMIC_RELAXED, __HIP_MEMORY_SCOPE_WORKGROUP);
    __hip_atomic_store((unsigned short*)p, b, __ATOMIC_RELAXED, __HIP_MEMORY_SCOPE_AGENT);
}
__device__ __forceinline__ void dstf(float* p, float v) {
    __hip_atomic_store(p, v, __ATOMIC_RELAXED, __HIP_MEMORY_SCOPE_WORKGROUP);
    __hip_atomic_store(p, v, __ATOMIC_RELAXED, __HIP_MEMORY_SCOPE_AGENT);
}

__device__ __forceinline__ void barsync() {
    MEMF();
    __builtin_amdgcn_s_barrier();
    MEMF();
}

// ---------- dual-slot flag barrier (32-block domain) ----------
__device__ __forceinline__ void arrive2(unsigned* fF, unsigned* fS, int cg, unsigned t) {
    if (threadIdx.x == 0) {
        __hip_atomic_store(fF + cg * 16, t, __ATOMIC_RELAXED, __HIP_MEMORY_SCOPE_WORKGROUP);
        __hip_atomic_store(fS + cg * 16, t, __ATOMIC_RELAXED, __HIP_MEMORY_SCOPE_AGENT);
    }
}
// fast poll (volatile, L2) with sticky timeout-flip to agent poll (L3)
__device__ __forceinline__ void gwait2(const unsigned* fF, const unsigned* fS,
                                       unsigned t, int& useFast) {
    if (threadIdx.x < 64) {
        int lane = threadIdx.x & 31;
        if (useFast) {
            int it = 0;
            for (;;) {
                unsigned v = *(volatile const unsigned*)(fF + lane * 16);
                if (__all(v >= t)) return;
                if (++it > 4096) { useFast = 0; break; }
            }
        }
        int it = 0;
        for (;;) {
            unsigned v = __hip_atomic_load(fS + lane * 16, __ATOMIC_RELAXED,
                                           __HIP_MEMORY_SCOPE_AGENT);
            if (__all(v >= t)) return;
            if (++it > (1 << 16)) return;  // failsafe: fail visibly, don't hang
        }
    }
}
__device__ __forceinline__ void gbar2(unsigned* fF, unsigned* fS, int cg,
                                      unsigned t, int& useFast) {
    asm volatile("s_waitcnt vmcnt(0)" ::: "memory");
    barsync();
    arrive2(fF, fS, cg, t);
    gwait2(fF, fS, t, useFast);
    barsync();
}

// stage 16 rows x 1024 f16 into LDS (pitch 1032). slow: agent loads (r10-proven).
__device__ __forceinline__ void stage16s(const f16* __restrict__ src,
                                         f16* __restrict__ stg, int tid) {
    unsigned long long a[16];
    #pragma unroll
    for (int i = 0; i < 16; ++i)
        a[i] = cload64(src + i * NU + tid * 4);
    MEMF();
    #pragma unroll
    for (int i = 0; i < 16; ++i)
        *(f16x4*)(&stg[i * 1032 + tid * 4]) = __builtin_bit_cast(f16x4, a[i]);
}
// fast: volatile loads (L1-bypass; compiler-managed waitcnts, no asm hazards)
__device__ __forceinline__ void stage16f(const f16* __restrict__ src,
                                         f16* __restrict__ stg, int tid) {
    unsigned long long a[16];
    #pragma unroll
    for (int i = 0; i < 16; ++i)
        a[i] = *(volatile const unsigned long long*)(src + i * NU + tid * 4);
    MEMF();
    #pragma unroll
    for (int i = 0; i < 16; ++i)
        *(f16x4*)(&stg[i * 1032 + tid * 4]) = __builtin_bit_cast(f16x4, a[i]);
}

// ---------------- embedding ----------------
__global__ void embed_kernel(const int* __restrict__ x, const float* __restrict__ emb,
                             f16* __restrict__ seq0) {
    int row = blockIdx.x;           // t*NB + b
    int t = row >> 5, b = row & 31;
    int e = threadIdx.x;
    int idx = x[b * NT + t];
    seq0[row * NE + e] = (f16)emb[idx * NE + e];
}

// ---------------- weight transpose+convert: WT[n][k] (f16) = W[k][n] (f32) ----------------
__global__ void wconv(const float* __restrict__ Wg, const float* __restrict__ Wc,
                      f16* __restrict__ WgT, f16* __restrict__ WcT, int K2) {
    __shared__ float tile[32][33];
    int mat = blockIdx.z & 1;
    const float* in = mat ? Wc : Wg;
    f16* outp = mat ? WcT : WgT;
    int N = mat ? 1024 : 2048;
    int by = blockIdx.y;
    if (by * 32 >= N) return;
    int k0 = blockIdx.x * 32, n0 = by * 32;
    int tx = threadIdx.x & 31, ty = threadIdx.x >> 5;  // 32 x 8
    #pragma unroll
    for (int i = 0; i < 4; ++i) {
        int r = ty * 4 + i;
        tile[r][tx] = in[(size_t)(k0 + r) * N + n0 + tx];
    }
    __syncthreads();
    #pragma unroll
    for (int i = 0; i < 4; ++i) {
        int rn = ty * 4 + i;
        outp[(size_t)(n0 + rn) * K2 + k0 + tx] = (f16)tile[tx][rn];
    }
}

// ---------------- input-projection GEMM, f16 transposed-weight edition ----------------
__launch_bounds__(256)
__global__ void gemm_projT(const f16* __restrict__ A, int lda, int K,
                           const f16* __restrict__ WgT, const f16* __restrict__ WcT, int K2,
                           const float* __restrict__ bg, const float* __restrict__ bc,
                           f16* __restrict__ proj) {
    __shared__ f16 As[128][40];
    __shared__ f16 Bs[128][40];
    int cb = blockIdx.y;
    const f16* Bsrc; int outcol; const float* bias;
    if (cb < 16) { Bsrc = WgT + (size_t)cb * 128 * K2; outcol = cb * 128; bias = bg + cb * 128; }
    else { Bsrc = WcT + (size_t)(cb - 16) * 128 * K2; outcol = 2048 + (cb - 16) * 128; bias = bc + (cb - 16) * 128; }
    int m0 = blockIdx.x * 128;
    int tid = threadIdx.x;
    int w = tid >> 6, l = tid & 63;
    int wm = w & 1, wn = w >> 1;
    f32x4 acc[4][4] = {};
    for (int k0 = 0; k0 < K; k0 += 32) {
        __syncthreads();
        #pragma unroll
        for (int p = 0; p < 2; ++p) {
            int e = (p * 256 + tid) * 8;
            int r = e >> 5, kq = e & 31;
            f16x8 v = *(const f16x8*)(A + (size_t)(m0 + r) * lda + k0 + kq);
            *(f16x8*)(&As[r][kq]) = v;
        }
        #pragma unroll
        for (int p = 0; p < 2; ++p) {
            int e = (p * 256 + tid) * 8;
            int r = e >> 5, kq = e & 31;
            f16x8 v = *(const f16x8*)(Bsrc + (size_t)r * K2 + k0 + kq);
            *(f16x8*)(&Bs[r][kq]) = v;
        }
        __syncthreads();
        int kq = (l >> 4) * 8;
        f16x8 a[4], b[4];
        #pragma unroll
        for (int i = 0; i < 4; ++i) a[i] = *(const f16x8*)(&As[wm * 64 + i * 16 + (l & 15)][kq]);
        #pragma unroll
        for (int j = 0; j < 4; ++j) b[j] = *(const f16x8*)(&Bs[wn * 64 + j * 16 + (l & 15)][kq]);
        #pragma unroll
        for (int i = 0; i < 4; ++i)
            #pragma unroll
            for (int j = 0; j < 4; ++j)
                acc[i][j] = __builtin_amdgcn_mfma_f32_16x16x32_f16(a[i], b[j], acc[i][j], 0, 0, 0);
    }
    int lr = (l >> 4) * 4, lc = l & 15;
    #pragma unroll
    for (int i = 0; i < 4; ++i) {
        #pragma unroll
        for (int j = 0; j < 4; ++j) {
            int gcol = wn * 64 + j * 16 + lc;
            float bia = bias[gcol];
            #pragma unroll
            for (int q = 0; q < 4; ++q) {
                int grow = m0 + wm * 64 + i * 16 + lr + q;
                proj[(size_t)grow * 3072 + outcol + gcol] = (f16)(acc[i][j][q] + bia);
            }
        }
    }
}

// ---------------- input-projection GEMM (fallback, f32 weights) ----------------
__launch_bounds__(256)
__global__ void gemm_proj(const f16* __restrict__ A, int lda, int K,
                          const float* __restrict__ Wg, const float* __restrict__ Wc,
                          const float* __restrict__ bg, const float* __restrict__ bc,
                          f16* __restrict__ proj) {
    __shared__ f16 As[128][40];
    __shared__ f16 Bs[128][40];
    int cb = blockIdx.y;
    const float* Bsrc; int ldb, outcol; const float* bias;
    if (cb < 16) { Bsrc = Wg + cb * 128; ldb = 2 * NU; outcol = cb * 128; bias = bg + cb * 128; }
    else { Bsrc = Wc + (cb - 16) * 128; ldb = NU; outcol = 2 * NU + (cb - 16) * 128; bias = bc + (cb - 16) * 128; }
    int m0 = blockIdx.x * 128;
    int tid = threadIdx.x;
    int w = tid >> 6, l = tid & 63;
    int wm = w & 1, wn = w >> 1;
    f32x4 acc[4][4] = {};
    for (int k0 = 0; k0 < K; k0 += 32) {
        __syncthreads();
        #pragma unroll
        for (int p = 0; p < 2; ++p) {
            int e = (p * 256 + tid) * 8;
            int r = e >> 5, kq = e & 31;
            f16x8 v = *(const f16x8*)(A + (size_t)(m0 + r) * lda + k0 + kq);
            *(f16x8*)(&As[r][kq]) = v;
        }
        #pragma unroll
        for (int p = 0; p < 4; ++p) {
            int k = p * 8 + (tid >> 5);
            int n = (tid & 31) * 4;
            float4 v = *(const float4*)(Bsrc + (size_t)(k0 + k) * ldb + n);
            Bs[n + 0][k] = (f16)v.x; Bs[n + 1][k] = (f16)v.y;
            Bs[n + 2][k] = (f16)v.z; Bs[n + 3][k] = (f16)v.w;
        }
        __syncthreads();
        int kq = (l >> 4) * 8;
        f16x8 a[4], b[4];
        #pragma unroll
        for (int i = 0; i < 4; ++i) a[i] = *(const f16x8*)(&As[wm * 64 + i * 16 + (l & 15)][kq]);
        #pragma unroll
        for (int j = 0; j < 4; ++j) b[j] = *(const f16x8*)(&Bs[wn * 64 + j * 16 + (l & 15)][kq]);
        #pragma unroll
        for (int i = 0; i < 4; ++i)
            #pragma unroll
            for (int j = 0; j < 4; ++j)
                acc[i][j] = __builtin_amdgcn_mfma_f32_16x16x32_f16(a[i], b[j], acc[i][j], 0, 0, 0);
    }
    int lr = (l >> 4) * 4, lc = l & 15;
    #pragma unroll
    for (int i = 0; i < 4; ++i) {
        #pragma unroll
        for (int j = 0; j < 4; ++j) {
            int gcol = wn * 64 + j * 16 + lc;
            float bia = bias[gcol];
            #pragma unroll
            for (int q = 0; q < 4; ++q) {
                int grow = m0 + wm * 64 + i * 16 + lr + q;
                proj[(size_t)grow * 3072 + outcol + gcol] = (f16)(acc[i][j][q] + bia);
            }
        }
    }
}

// ---------------- final FC ----------------
__launch_bounds__(256)
__global__ void gemm_fc(const f16* __restrict__ y, const float* __restrict__ W,
                        const float* __restrict__ bias, float* __restrict__ out) {
    __shared__ f16 As[128][40];
    __shared__ f16 Bs[128][40];
    int m0 = blockIdx.x * 128;
    int tid = threadIdx.x;
    int w = tid >> 6, l = tid & 63;
    int wm = w & 1, wn = w >> 1;
    f32x4 acc[4][4] = {};
    for (int k0 = 0; k0 < 2048; k0 += 32) {
        __syncthreads();
        #pragma unroll
        for (int p = 0; p < 2; ++p) {
            int e = (p * 256 + tid) * 8;
            int r = e >> 5, kq = e & 31;
            int grow = m0 + r;                 // row = b*256 + t
            int b = grow >> 8, t = grow & 255;
            f16x8 v = *(const f16x8*)(y + (size_t)(t * 32 + b) * 2048 + k0 + kq);
            *(f16x8*)(&As[r][kq]) = v;
        }
        #pragma unroll
        for (int p = 0; p < 4; ++p) {
            int k = p * 8 + (tid >> 5);
            int n = (tid & 31) * 4;
            float4 v = *(const float4*)(W + (size_t)(k0 + k) * 128 + n);
            Bs[n + 0][k] = (f16)v.x; Bs[n + 1][k] = (f16)v.y;
            Bs[n + 2][k] = (f16)v.z; Bs[n + 3][k] = (f16)v.w;
        }
        __syncthreads();
        int kq = (l >> 4) * 8;
        f16x8 a[4], b[4];
        #pragma unroll
        for (int i = 0; i < 4; ++i) a[i] = *(const f16x8*)(&As[wm * 64 + i * 16 + (l & 15)][kq]);
        #pragma unroll
        for (int j = 0; j < 4; ++j) b[j] = *(const f16x8*)(&Bs[wn * 64 + j * 16 + (l & 15)][kq]);
        #pragma unroll
        for (int i = 0; i < 4; ++i)
            #pragma unroll
            for (int j = 0; j < 4; ++j)
                acc[i][j] = __builtin_amdgcn_mfma_f32_16x16x32_f16(a[i], b[j], acc[i][j], 0, 0, 0);
    }
    int lr = (l >> 4) * 4, lc = l & 15;
    #pragma unroll
    for (int i = 0; i < 4; ++i) {
        #pragma unroll
        for (int j = 0; j < 4; ++j) {
            int gcol = wn * 64 + j * 16 + lc;
            float bia = bias[gcol];
            #pragma unroll
            for (int q = 0; q < 4; ++q) {
                int grow = m0 + wm * 64 + i * 16 + lr + q;
                out[(size_t)grow * 128 + gcol] = acc[i][j][q] + bia;
            }
        }
    }
}

// ---------------- recurrent bidirectional GRU layer ----------------
// r10 data path + XCD-local fast mode gated by a SOUND two-round staleness probe.
// Grid 256; chain c = bid&7 (c>=4 exit): 4 chains x 32 blocks; under mod-8 XCD
// round-robin a chain is XCD-local. Writers DUAL-PUBLISH (plain->L2 + agent->L3)
// all cross-block data & flags, so any reader mode is correct. Probe: write A,
// slow-bar, volatile-read all peers (seeds caches); write B, slow-bar, volatile
// re-read — passes only if re-reads are coherent (same-XCD AND volatile bypasses
// stale caches), which is exactly what the fast loop requires. Flag polling is
// additionally adaptive (timeout -> sticky agent fallback).
__launch_bounds__(256)
__global__ void gru_layer(
    const f16* __restrict__ proj_fw, const f16* __restrict__ proj_bw,
    const float* __restrict__ Wgh_fw, const float* __restrict__ Wgh_bw,
    const float* __restrict__ Wch_fw, const float* __restrict__ Wch_bw,
    const float* __restrict__ h0_fw, const float* __restrict__ h0_bw,
    f16* __restrict__ h16, f16* __restrict__ rh16, float* __restrict__ u32,
    f16* __restrict__ y, float* __restrict__ st_fw, float* __restrict__ st_bw,
    unsigned* __restrict__ ctrl)
{
    extern __shared__ f16 smem[];
    f16* stg    = smem;             // [16][1032]
    f16* Wc_lds = smem + 16 * 1032; // [32][1032]
    __shared__ int s_fast;

    int bid = blockIdx.x, tid = threadIdx.x;
    int c = bid & 7;
    if (c >= 4) return;             // 4 chains x 32 blocks active
    int cg   = bid >> 3;            // col group 0..31
    int dir  = c >> 1, rh_i = c & 1;
    int R0   = rh_i * 16;
    int gcb  = cg * 64;
    int ccb  = cg * 32;

    const f16*  proj = dir ? proj_bw : proj_fw;
    const float* Wgh = dir ? Wgh_bw : Wgh_fw;
    const float* Wch = dir ? Wch_bw : Wch_fw;
    const float* h0  = dir ? h0_bw  : h0_fw;
    f16*   h16d  = h16  + dir * (NB * NU);
    f16*   rh16d = rh16 + dir * (NB * NU);
    float* u32d  = u32  + dir * (NB * NU);
    unsigned* base = ctrl + c * 2048;
    unsigned* fF   = base;           // 32 fast flags x 64B stride
    unsigned* fS   = base + 512;     // 32 slow flags x 64B stride
    unsigned* chkd = base + 1024;    // 32 probe slots x 64B stride

    const f16* hsrc  = h16d  + (size_t)R0 * NU;
    const f16* rhsrc = rh16d + (size_t)R0 * NU;

    int w = tid >> 6, l = tid & 63;
    int lc = l & 15, lr = (l >> 4) * 4, kq = (l >> 4) * 8;

    // ---- Wc slice (32 cols) into LDS ----
    {
        int j2 = tid & 31;
        for (int k = tid >> 5; k < NU; k += 8)
            Wc_lds[j2 * 1032 + k] = (f16)Wch[(size_t)k * 1024 + ccb + j2];
    }

    // ---- Wg fragments -> registers ----
    f16x8 wgf[32];
    {
        int col = gcb + w * 16 + lc;
        #pragma unroll
        for (int kt = 0; kt < 32; ++kt) {
            f16x8 t;
            #pragma unroll
            for (int e = 0; e < 8; ++e)
                t[e] = (f16)Wgh[(size_t)(kt * 32 + kq + e) * 2048 + col];
            wgf[kt] = t;
        }
    }

    // ---- init h (dual-publish; disjoint slices) ----
    {
        int base2 = (rh_i * 32 + cg) * 512;
        for (int i = tid; i < 512; i += 256)
            dst16(h16d + base2 + i, (f16)h0[base2 + i]);
    }
    f32x4 hreg = {};
    if (w < 2) {
        #pragma unroll
        for (int q = 0; q < 4; ++q)
            hreg[q] = h0[(size_t)(R0 + lr + q) * NU + ccb + w * 16 + lc];
    }

    int gc  = gcb + w * 16 + lc;           // gate col (this wave)
    int cc  = ccb + (w & 1) * 16 + lc;     // cand col (waves 0-1)
    int cc2 = 2048 + cc;
    bool rblk = (cg < 16);                 // block-uniform

    // ---- prefetch step-0 proj operands ----
    f16 pg[4], pc[4];
    {
        int td0 = dir ? (NT - 1) : 0;
        const f16* pr = proj + (size_t)td0 * NB * 3072;
        #pragma unroll
        for (int q = 0; q < 4; ++q) {
            pg[q] = pr[(size_t)(R0 + lr + q) * 3072 + gc];
            pc[q] = pr[(size_t)(R0 + lr + q) * 3072 + cc2];
        }
    }

    // ---- two-round staleness probe (slow barriers throughout) ----
    unsigned bc = 1;
    int slow0 = 0;  // forced-slow mode flag for probe barriers
    if (tid == 0)
        __hip_atomic_store(chkd + cg * 16, (unsigned)bid + 101u,
                           __ATOMIC_RELAXED, __HIP_MEMORY_SCOPE_WORKGROUP);
    gbar2(fF, fS, cg, bc, slow0);          // slow: drains token + h init
    int okA = 1, okB = 1;
    if (tid < 64) {
        int lane = tid & 31;
        unsigned v = *(volatile const unsigned*)(chkd + lane * 16);  // seeds caches
        okA = __all(v == (unsigned)(lane * 8 + c) + 101u);
    }
    ++bc;
    if (tid == 0)
        __hip_atomic_store(chkd + cg * 16, (unsigned)bid + 50001u,
                           __ATOMIC_RELAXED, __HIP_MEMORY_SCOPE_WORKGROUP);
    gbar2(fF, fS, cg, bc, slow0);
    if (tid < 64) {
        int lane = tid & 31;
        unsigned v = *(volatile const unsigned*)(chkd + lane * 16);  // re-read: stale?
        okB = __all(v == (unsigned)(lane * 8 + c) + 50001u);
    }
    if (tid == 0) s_fast = (okA && okB) ? 1 : 0;
    barsync();
    int fastmode = s_fast;
    int useFast = fastmode;

    auto run = [&](auto tag) {
        constexpr bool F = decltype(tag)::value;
        for (int tl = 0; tl < NT; ++tl) {
            int td = dir ? (NT - 1 - tl) : tl;

            // ---- stage h (16 rows) -> LDS ----
            if constexpr (F) stage16f(hsrc, stg, tid);
            else             stage16s(hsrc, stg, tid);
            asm volatile("s_waitcnt lgkmcnt(0)" ::: "memory");
            __builtin_amdgcn_sched_barrier(0);
            barsync();

            // ---- phase A: ru = sigmoid(proj_g + h @ Wg_h) ----
            {
                const f16* ap = &stg[lc * 1032 + kq];
                f32x4 acc0 = {}, acc1 = {};
                #pragma unroll
                for (int kt = 0; kt < 32; kt += 2) {
                    f16x8 a0 = *(const f16x8*)(ap + kt * 32);
                    f16x8 a1 = *(const f16x8*)(ap + (kt + 1) * 32);
                    acc0 = __builtin_amdgcn_mfma_f32_16x16x32_f16(a0, wgf[kt], acc0, 0, 0, 0);
                    acc1 = __builtin_amdgcn_mfma_f32_16x16x32_f16(a1, wgf[kt + 1], acc1, 0, 0, 0);
                }
                f32x4 acc = acc0 + acc1;
                #pragma unroll
                for (int q = 0; q < 4; ++q) {
                    int br = lr + q;           // local row
                    float pre = acc[q] + (float)pg[q];
                    float sg = 1.f / (1.f + __expf(-pre));
                    if (rblk) {
                        float hv = (float)stg[br * 1032 + gc];
                        dst16(rh16d + (size_t)(R0 + br) * NU + gc, (f16)(sg * hv));
                    } else {
                        dstf(u32d + (size_t)(R0 + br) * NU + gc - NU, sg);
                    }
                }
            }
            ++bc;
            gbar2(fF, fS, cg, bc, useFast);   // barrier #1: rh/u published

            // ---- early u loads (overlap with rh stage) ----
            float uu[4];
            if (w < 2) {
                #pragma unroll
                for (int q = 0; q < 4; ++q) {
                    const float* up = u32d + (size_t)(R0 + lr + q) * NU + cc;
                    uu[q] = F ? *(volatile const float*)up : cloadf(up);
                }
            }

            // ---- stage rh (16 rows) -> LDS ----
            if constexpr (F) stage16f(rhsrc, stg, tid);
            else             stage16s(rhsrc, stg, tid);
            asm volatile("s_waitcnt lgkmcnt(0)" ::: "memory");
            __builtin_amdgcn_sched_barrier(0);
            barsync();

            // ---- phase B: c = tanh(proj_c + (r*h) @ Wc_h); h = u*h + (1-u)*c ----
            if (w < 2) {
                const f16* ap = &stg[lc * 1032 + kq];
                const f16* bptr = Wc_lds + ((w & 1) * 16 + lc) * 1032 + kq;
                f32x4 acc0 = {}, acc1 = {};
                #pragma unroll
                for (int kt = 0; kt < 32; kt += 2) {
                    f16x8 a0 = *(const f16x8*)(ap + kt * 32);
                    f16x8 a1 = *(const f16x8*)(ap + (kt + 1) * 32);
                    f16x8 b0 = *(const f16x8*)(bptr + kt * 32);
                    f16x8 b1 = *(const f16x8*)(bptr + kt * 32 + 32);
                    acc0 = __builtin_amdgcn_mfma_f32_16x16x32_f16(a0, b0, acc0, 0, 0, 0);
                    acc1 = __builtin_amdgcn_mfma_f32_16x16x32_f16(a1, b1, acc1, 0, 0, 0);
                }
                f32x4 acc = acc0 + acc1;
                #pragma unroll
                for (int q = 0; q < 4; ++q) {
                    int br = R0 + lr + q;      // global row
                    float pre = acc[q] + (float)pc[q];
                    float e2 = __expf(2.f * pre);
                    float cv = 1.f - 2.f / (e2 + 1.f);   // tanh(pre)
                    float hn = uu[q] * hreg[q] + (1.f - uu[q]) * cv;
                    hreg[q] = hn;
                    dst16(h16d + (size_t)br * NU + cc, (f16)hn);
                }
            }
            ++bc;
            // barrier #2 inline: drain h16, arrive, window work, wait
            asm volatile("s_waitcnt vmcnt(0)" ::: "memory");
            barsync();
            arrive2(fF, fS, cg, bc);
            // window: y / final-state stores
            if (w < 2) {
                #pragma unroll
                for (int q = 0; q < 4; ++q) {
                    int br = R0 + lr + q;
                    y[(size_t)(td * NB + br) * 2048 + dir * NU + cc] = (f16)hreg[q];
                    if (tl == NT - 1)
                        (dir ? st_bw : st_fw)[(size_t)br * NU + cc] = hreg[q];
                }
            }
            // window: prefetch next step's proj operands
            if (tl + 1 < NT) {
                int tdn = dir ? (NT - 2 - tl) : (tl + 1);
                const f16* pr = proj + (size_t)tdn * NB * 3072;
                #pragma unroll
                for (int q = 0; q < 4; ++q) {
                    pg[q] = pr[(size_t)(R0 + lr + q) * 3072 + gc];
                    pc[q] = pr[(size_t)(R0 + lr + q) * 3072 + cc2];
                }
            }
            gwait2(fF, fS, bc, useFast);
            barsync();
        }
    };
    if (fastmode) run(BoolT<true>{});
    else          run(BoolT<false>{});
}

// ---------------- host launch ----------------
extern "C" void kernel_launch(void* const* d_in, const int* in_sizes, int n_in,
                              void* d_out, int out_size, void* d_ws, size_t ws_size,
                              hipStream_t stream) {
    const int*   x   = (const int*)  d_in[0];
    const float* emb = (const float*)d_in[1];
    const float* fcW = (const float*)d_in[2];
    const float* fcb = (const float*)d_in[3];
    float* out = (float*)d_out;

    char* ws = (char*)d_ws;
    size_t off = 0;
    f16* seq0   = (f16*)(ws + off); off += (size_t)8192 * 256 * 2;
    f16* ybuf0  = (f16*)(ws + off); off += (size_t)8192 * 2048 * 2;
    f16* ybuf1  = (f16*)(ws + off); off += (size_t)8192 * 2048 * 2;
    f16* projfw = (f16*)(ws + off); off += (size_t)8192 * 3072 * 2;
    f16* projbw = (f16*)(ws + off); off += (size_t)8192 * 3072 * 2;
    f16*   h16  = (f16*)(ws + off);   off += 2 * 32 * 1024 * 2;
    f16*   rh16 = (f16*)(ws + off);   off += 2 * 32 * 1024 * 2;
    float* u32  = (float*)(ws + off); off += 2 * 32 * 1024 * 4;
    unsigned* ctrl = (unsigned*)(ws + off); off += 3 * 32768;  // per layer: 8192 u32
    // per-layer-reused f16 transposed-weight slot (max-layer sizes, K2=3072)
    f16* WgT_fw = (f16*)(ws + off); off += (size_t)2048 * 3072 * 2;
    f16* WgT_bw = (f16*)(ws + off); off += (size_t)2048 * 3072 * 2;
    f16* WcT_fw = (f16*)(ws + off); off += (size_t)1024 * 3072 * 2;
    f16* WcT_bw = (f16*)(ws + off); off += (size_t)1024 * 3072 * 2;
    bool cvt = (ws_size >= off);   // fall back to f32 gemm if slot doesn't fit

    hipFuncSetAttribute((const void*)gru_layer,
                        hipFuncAttributeMaxDynamicSharedMemorySize, 99072);

    hipMemsetAsync(ctrl, 0, 3 * 32768, stream);
    embed_kernel<<<dim3(8192), dim3(256), 0, stream>>>(x, emb, seq0);

    const f16* lin = seq0; int lda = 256, K = 256;
    f16* ybufs[2] = {ybuf0, ybuf1};
    for (int l = 0; l < 3; ++l) {
        const float* Wg_fw = (const float*)d_in[4 + l * 10 + 0];
        const float* bg_fw = (const float*)d_in[4 + l * 10 + 1];
        const float* Wc_fw = (const float*)d_in[4 + l * 10 + 2];
        const float* bc_fw = (const float*)d_in[4 + l * 10 + 3];
        const float* h0_fw = (const float*)d_in[4 + l * 10 + 4];
        const float* Wg_bw = (const float*)d_in[4 + l * 10 + 5];
        const float* bg_bw = (const float*)d_in[4 + l * 10 + 6];
        const float* Wc_bw = (const float*)d_in[4 + l * 10 + 7];
        const float* bc_bw = (const float*)d_in[4 + l * 10 + 8];
        const float* h0_bw = (const float*)d_in[4 + l * 10 + 9];
        int din = (l == 0) ? 256 : 2048;
        int K2 = din + 1024;

        if (cvt) {
            wconv<<<dim3(K2 / 32, 64, 2), dim3(256), 0, stream>>>(Wg_fw, Wc_fw, WgT_fw, WcT_fw, K2);
            wconv<<<dim3(K2 / 32, 64, 2), dim3(256), 0, stream>>>(Wg_bw, Wc_bw, WgT_bw, WcT_bw, K2);
            gemm_projT<<<dim3(64, 24), dim3(256), 0, stream>>>(lin, lda, K, WgT_fw, WcT_fw, K2, bg_fw, bc_fw, projfw);
            gemm_projT<<<dim3(64, 24), dim3(256), 0, stream>>>(lin, lda, K, WgT_bw, WcT_bw, K2, bg_bw, bc_bw, projbw);
        } else {
            gemm_proj<<<dim3(64, 24), dim3(256), 0, stream>>>(lin, lda, K, Wg_fw, Wc_fw, bg_fw, bc_fw, projfw);
            gemm_proj<<<dim3(64, 24), dim3(256), 0, stream>>>(lin, lda, K, Wg_bw, Wc_bw, bg_bw, bc_bw, projbw);
        }

        const float* Wgh_fw = Wg_fw + (size_t)din * 2048;
        const float* Wgh_bw = Wg_bw + (size_t)din * 2048;
        const float* Wch_fw = Wc_fw + (size_t)din * 1024;
        const float* Wch_bw = Wc_bw + (size_t)din * 1024;
        f16* yout = ybufs[l & 1];
        float* stfw = out + 1048576 + l * 32768;
        float* stbw = out + 1048576 + 98304 + l * 32768;
        unsigned* cnt = ctrl + l * 8192;

        gru_layer<<<dim3(256), dim3(256), 99072, stream>>>(
            projfw, projbw, Wgh_fw, Wgh_bw, Wch_fw, Wch_bw, h0_fw, h0_bw,
            h16, rh16, u32, yout, stfw, stbw, cnt);
        lin = yout; lda = 2048; K = 2048;
    }

    gemm_fc<<<dim3(64), dim3(256), 0, stream>>>(ybufs[0], fcW, fcb, out);
}

// Round 13
// 11528.635 us; speedup vs baseline: 2.1036x; 2.1036x over previous
//
#include <hip/hip_runtime.h>

typedef _Float16 f16;
typedef _Float16 f16x4 __attribute__((ext_vector_type(4)));
typedef _Float16 f16x8 __attribute__((ext_vector_type(8)));
typedef float f32x4 __attribute__((ext_vector_type(4)));

#define NB 32
#define NT 256
#define NE 256
#define NU 1024
#define NV 128

#define MEMF() asm volatile("" ::: "memory")

template<bool B> struct BoolT { static constexpr bool value = B; };

// ---------- agent-coherent (cross-XCD, L3-level) helpers (r10-proven) ----------
__device__ __forceinline__ unsigned long long cload64(const f16* p) {
    return __hip_atomic_load((const unsigned long long*)p, __ATOMIC_RELAXED,
                             __HIP_MEMORY_SCOPE_AGENT);
}
__device__ __forceinline__ float cloadf(const float* p) {
    return __hip_atomic_load(p, __ATOMIC_RELAXED, __HIP_MEMORY_SCOPE_AGENT);
}
__device__ __forceinline__ void cstoref(float* p, float v) {
    __hip_atomic_store(p, v, __ATOMIC_RELAXED, __HIP_MEMORY_SCOPE_AGENT);
}
__device__ __forceinline__ void cstore16(f16* p, f16 v) {
    __hip_atomic_store((unsigned short*)p, __builtin_bit_cast(unsigned short, v),
                       __ATOMIC_RELAXED, __HIP_MEMORY_SCOPE_AGENT);
}

__device__ __forceinline__ void barsync() {
    MEMF();
    __builtin_amdgcn_s_barrier();
    MEMF();
}

// ---------- sc0 (L1-bypass, XCD-L2) primitives: waitcnt INSIDE the asm ----------
__device__ __forceinline__ unsigned ld_sc0_wait(const unsigned* p) {
    unsigned v;
    asm volatile("global_load_dword %0, %1, off sc0\n\ts_waitcnt vmcnt(0)"
                 : "=&v"(v) : "v"(p) : "memory");
    return v;
}
__device__ __forceinline__ void ld4f_sc0(const float* p0, const float* p1,
                                         const float* p2, const float* p3, float* o) {
    asm volatile(
        "global_load_dword %0, %4, off sc0\n\t"
        "global_load_dword %1, %5, off sc0\n\t"
        "global_load_dword %2, %6, off sc0\n\t"
        "global_load_dword %3, %7, off sc0\n\t"
        "s_waitcnt vmcnt(0)"
        : "=&v"(o[0]), "=&v"(o[1]), "=&v"(o[2]), "=&v"(o[3])
        : "v"(p0), "v"(p1), "v"(p2), "v"(p3) : "memory");
}
__device__ __forceinline__ void st_plain_u32(unsigned* p, unsigned t) {
    asm volatile("global_store_dword %0, %1, off" :: "v"(p), "v"(t) : "memory");
}

// stage 16 rows x 1024 f16 into LDS (pitch 1032). SLOW: agent loads (r10-proven).
__device__ __forceinline__ void stage16s(const f16* __restrict__ src,
                                         f16* __restrict__ stg, int tid) {
    unsigned long long a[16];
    #pragma unroll
    for (int i = 0; i < 16; ++i)
        a[i] = cload64(src + i * NU + tid * 4);
    MEMF();
    #pragma unroll
    for (int i = 0; i < 16; ++i)
        *(f16x4*)(&stg[i * 1032 + tid * 4]) = __builtin_bit_cast(f16x4, a[i]);
}
// FAST: 16 sc0 loads in ONE asm block, single vmcnt(0) inside, early-clobber outs.
__device__ __forceinline__ void stage16f(const f16* __restrict__ src,
                                         f16* __restrict__ stg, int tid) {
    const char* b = (const char*)(src + tid * 4);
    unsigned long long o0,o1,o2,o3,o4,o5,o6,o7,o8,o9,o10,o11,o12,o13,o14,o15;
    asm volatile(
        "global_load_dwordx2 %[v0],  %[a0], off sc0\n\t"
        "global_load_dwordx2 %[v1],  %[a0], off offset:2048 sc0\n\t"
        "global_load_dwordx2 %[v2],  %[a1], off sc0\n\t"
        "global_load_dwordx2 %[v3],  %[a1], off offset:2048 sc0\n\t"
        "global_load_dwordx2 %[v4],  %[a2], off sc0\n\t"
        "global_load_dwordx2 %[v5],  %[a2], off offset:2048 sc0\n\t"
        "global_load_dwordx2 %[v6],  %[a3], off sc0\n\t"
        "global_load_dwordx2 %[v7],  %[a3], off offset:2048 sc0\n\t"
        "global_load_dwordx2 %[v8],  %[a4], off sc0\n\t"
        "global_load_dwordx2 %[v9],  %[a4], off offset:2048 sc0\n\t"
        "global_load_dwordx2 %[v10], %[a5], off sc0\n\t"
        "global_load_dwordx2 %[v11], %[a5], off offset:2048 sc0\n\t"
        "global_load_dwordx2 %[v12], %[a6], off sc0\n\t"
        "global_load_dwordx2 %[v13], %[a6], off offset:2048 sc0\n\t"
        "global_load_dwordx2 %[v14], %[a7], off sc0\n\t"
        "global_load_dwordx2 %[v15], %[a7], off offset:2048 sc0\n\t"
        "s_waitcnt vmcnt(0)"
        : [v0]"=&v"(o0), [v1]"=&v"(o1), [v2]"=&v"(o2), [v3]"=&v"(o3),
          [v4]"=&v"(o4), [v5]"=&v"(o5), [v6]"=&v"(o6), [v7]"=&v"(o7),
          [v8]"=&v"(o8), [v9]"=&v"(o9), [v10]"=&v"(o10), [v11]"=&v"(o11),
          [v12]"=&v"(o12), [v13]"=&v"(o13), [v14]"=&v"(o14), [v15]"=&v"(o15)
        : [a0]"v"(b), [a1]"v"(b + 4096), [a2]"v"(b + 8192), [a3]"v"(b + 12288),
          [a4]"v"(b + 16384), [a5]"v"(b + 20480), [a6]"v"(b + 24576), [a7]"v"(b + 28672)
        : "memory");
    unsigned long long oo[16] = {o0,o1,o2,o3,o4,o5,o6,o7,o8,o9,o10,o11,o12,o13,o14,o15};
    #pragma unroll
    for (int i = 0; i < 16; ++i)
        *(f16x4*)(&stg[i * 1032 + tid * 4]) = __builtin_bit_cast(f16x4, oo[i]);
}

// ---------- dual-mode flag barrier over the chain's 32 blocks ----------
template<bool F> __device__ __forceinline__ void gwaitx(const unsigned* fF,
                                                        const unsigned* fS, unsigned t) {
    if (threadIdx.x < 64) {
        int lane = threadIdx.x & 31;
        int it = 0;
        for (;;) {
            unsigned v;
            if constexpr (F) v = ld_sc0_wait(fF + lane * 16);
            else             v = __hip_atomic_load(fS + lane * 16, __ATOMIC_RELAXED,
                                                   __HIP_MEMORY_SCOPE_AGENT);
            if (__all(v >= t)) break;
            if (++it > 8192) break;  // failsafe: fail visibly, don't hang
        }
    }
}
template<bool F> __device__ __forceinline__ void arrivex(unsigned* fF, unsigned* fS,
                                                         int cg, unsigned t) {
    if (threadIdx.x == 0) {
        if constexpr (F) st_plain_u32(fF + cg * 16, t);
        else __hip_atomic_store(fS + cg * 16, t, __ATOMIC_RELAXED,
                                __HIP_MEMORY_SCOPE_AGENT);
    }
}
template<bool F> __device__ __forceinline__ void gbarx(unsigned* fF, unsigned* fS,
                                                       int cg, unsigned t) {
    asm volatile("s_waitcnt vmcnt(0)" ::: "memory");
    barsync();
    arrivex<F>(fF, fS, cg, t);
    gwaitx<F>(fF, fS, t);
    barsync();
}

// ---------------- embedding ----------------
__global__ void embed_kernel(const int* __restrict__ x, const float* __restrict__ emb,
                             f16* __restrict__ seq0) {
    int row = blockIdx.x;           // t*NB + b
    int t = row >> 5, b = row & 31;
    int e = threadIdx.x;
    int idx = x[b * NT + t];
    seq0[row * NE + e] = (f16)emb[idx * NE + e];
}

// ---------------- weight transpose+convert: WT[n][k] (f16) = W[k][n] (f32) ----------------
__global__ void wconv(const float* __restrict__ Wg, const float* __restrict__ Wc,
                      f16* __restrict__ WgT, f16* __restrict__ WcT, int K2) {
    __shared__ float tile[32][33];
    int mat = blockIdx.z & 1;
    const float* in = mat ? Wc : Wg;
    f16* outp = mat ? WcT : WgT;
    int N = mat ? 1024 : 2048;
    int by = blockIdx.y;
    if (by * 32 >= N) return;
    int k0 = blockIdx.x * 32, n0 = by * 32;
    int tx = threadIdx.x & 31, ty = threadIdx.x >> 5;  // 32 x 8
    #pragma unroll
    for (int i = 0; i < 4; ++i) {
        int r = ty * 4 + i;
        tile[r][tx] = in[(size_t)(k0 + r) * N + n0 + tx];
    }
    __syncthreads();
    #pragma unroll
    for (int i = 0; i < 4; ++i) {
        int rn = ty * 4 + i;
        outp[(size_t)(n0 + rn) * K2 + k0 + tx] = (f16)tile[tx][rn];
    }
}

// ---------------- input-projection GEMM, f16 transposed-weight edition ----------------
__launch_bounds__(256)
__global__ void gemm_projT(const f16* __restrict__ A, int lda, int K,
                           const f16* __restrict__ WgT, const f16* __restrict__ WcT, int K2,
                           const float* __restrict__ bg, const float* __restrict__ bc,
                           f16* __restrict__ proj) {
    __shared__ f16 As[128][40];
    __shared__ f16 Bs[128][40];
    int cb = blockIdx.y;
    const f16* Bsrc; int outcol; const float* bias;
    if (cb < 16) { Bsrc = WgT + (size_t)cb * 128 * K2; outcol = cb * 128; bias = bg + cb * 128; }
    else { Bsrc = WcT + (size_t)(cb - 16) * 128 * K2; outcol = 2048 + (cb - 16) * 128; bias = bc + (cb - 16) * 128; }
    int m0 = blockIdx.x * 128;
    int tid = threadIdx.x;
    int w = tid >> 6, l = tid & 63;
    int wm = w & 1, wn = w >> 1;
    f32x4 acc[4][4] = {};
    for (int k0 = 0; k0 < K; k0 += 32) {
        __syncthreads();
        #pragma unroll
        for (int p = 0; p < 2; ++p) {
            int e = (p * 256 + tid) * 8;
            int r = e >> 5, kq = e & 31;
            f16x8 v = *(const f16x8*)(A + (size_t)(m0 + r) * lda + k0 + kq);
            *(f16x8*)(&As[r][kq]) = v;
        }
        #pragma unroll
        for (int p = 0; p < 2; ++p) {
            int e = (p * 256 + tid) * 8;
            int r = e >> 5, kq = e & 31;
            f16x8 v = *(const f16x8*)(Bsrc + (size_t)r * K2 + k0 + kq);
            *(f16x8*)(&Bs[r][kq]) = v;
        }
        __syncthreads();
        int kq = (l >> 4) * 8;
        f16x8 a[4], b[4];
        #pragma unroll
        for (int i = 0; i < 4; ++i) a[i] = *(const f16x8*)(&As[wm * 64 + i * 16 + (l & 15)][kq]);
        #pragma unroll
        for (int j = 0; j < 4; ++j) b[j] = *(const f16x8*)(&Bs[wn * 64 + j * 16 + (l & 15)][kq]);
        #pragma unroll
        for (int i = 0; i < 4; ++i)
            #pragma unroll
            for (int j = 0; j < 4; ++j)
                acc[i][j] = __builtin_amdgcn_mfma_f32_16x16x32_f16(a[i], b[j], acc[i][j], 0, 0, 0);
    }
    int lr = (l >> 4) * 4, lc = l & 15;
    #pragma unroll
    for (int i = 0; i < 4; ++i) {
        #pragma unroll
        for (int j = 0; j < 4; ++j) {
            int gcol = wn * 64 + j * 16 + lc;
            float bia = bias[gcol];
            #pragma unroll
            for (int q = 0; q < 4; ++q) {
                int grow = m0 + wm * 64 + i * 16 + lr + q;
                proj[(size_t)grow * 3072 + outcol + gcol] = (f16)(acc[i][j][q] + bia);
            }
        }
    }
}

// ---------------- input-projection GEMM (fallback, f32 weights) ----------------
__launch_bounds__(256)
__global__ void gemm_proj(const f16* __restrict__ A, int lda, int K,
                          const float* __restrict__ Wg, const float* __restrict__ Wc,
                          const float* __restrict__ bg, const float* __restrict__ bc,
                          f16* __restrict__ proj) {
    __shared__ f16 As[128][40];
    __shared__ f16 Bs[128][40];
    int cb = blockIdx.y;
    const float* Bsrc; int ldb, outcol; const float* bias;
    if (cb < 16) { Bsrc = Wg + cb * 128; ldb = 2 * NU; outcol = cb * 128; bias = bg + cb * 128; }
    else { Bsrc = Wc + (cb - 16) * 128; ldb = NU; outcol = 2 * NU + (cb - 16) * 128; bias = bc + (cb - 16) * 128; }
    int m0 = blockIdx.x * 128;
    int tid = threadIdx.x;
    int w = tid >> 6, l = tid & 63;
    int wm = w & 1, wn = w >> 1;
    f32x4 acc[4][4] = {};
    for (int k0 = 0; k0 < K; k0 += 32) {
        __syncthreads();
        #pragma unroll
        for (int p = 0; p < 2; ++p) {
            int e = (p * 256 + tid) * 8;
            int r = e >> 5, kq = e & 31;
            f16x8 v = *(const f16x8*)(A + (size_t)(m0 + r) * lda + k0 + kq);
            *(f16x8*)(&As[r][kq]) = v;
        }
        #pragma unroll
        for (int p = 0; p < 4; ++p) {
            int k = p * 8 + (tid >> 5);
            int n = (tid & 31) * 4;
            float4 v = *(const float4*)(Bsrc + (size_t)(k0 + k) * ldb + n);
            Bs[n + 0][k] = (f16)v.x; Bs[n + 1][k] = (f16)v.y;
            Bs[n + 2][k] = (f16)v.z; Bs[n + 3][k] = (f16)v.w;
        }
        __syncthreads();
        int kq = (l >> 4) * 8;
        f16x8 a[4], b[4];
        #pragma unroll
        for (int i = 0; i < 4; ++i) a[i] = *(const f16x8*)(&As[wm * 64 + i * 16 + (l & 15)][kq]);
        #pragma unroll
        for (int j = 0; j < 4; ++j) b[j] = *(const f16x8*)(&Bs[wn * 64 + j * 16 + (l & 15)][kq]);
        #pragma unroll
        for (int i = 0; i < 4; ++i)
            #pragma unroll
            for (int j = 0; j < 4; ++j)
                acc[i][j] = __builtin_amdgcn_mfma_f32_16x16x32_f16(a[i], b[j], acc[i][j], 0, 0, 0);
    }
    int lr = (l >> 4) * 4, lc = l & 15;
    #pragma unroll
    for (int i = 0; i < 4; ++i) {
        #pragma unroll
        for (int j = 0; j < 4; ++j) {
            int gcol = wn * 64 + j * 16 + lc;
            float bia = bias[gcol];
            #pragma unroll
            for (int q = 0; q < 4; ++q) {
                int grow = m0 + wm * 64 + i * 16 + lr + q;
                proj[(size_t)grow * 3072 + outcol + gcol] = (f16)(acc[i][j][q] + bia);
            }
        }
    }
}

// ---------------- final FC ----------------
__launch_bounds__(256)
__global__ void gemm_fc(const f16* __restrict__ y, const float* __restrict__ W,
                        const float* __restrict__ bias, float* __restrict__ out) {
    __shared__ f16 As[128][40];
    __shared__ f16 Bs[128][40];
    int m0 = blockIdx.x * 128;
    int tid = threadIdx.x;
    int w = tid >> 6, l = tid & 63;
    int wm = w & 1, wn = w >> 1;
    f32x4 acc[4][4] = {};
    for (int k0 = 0; k0 < 2048; k0 += 32) {
        __syncthreads();
        #pragma unroll
        for (int p = 0; p < 2; ++p) {
            int e = (p * 256 + tid) * 8;
            int r = e >> 5, kq = e & 31;
            int grow = m0 + r;                 // row = b*256 + t
            int b = grow >> 8, t = grow & 255;
            f16x8 v = *(const f16x8*)(y + (size_t)(t * 32 + b) * 2048 + k0 + kq);
            *(f16x8*)(&As[r][kq]) = v;
        }
        #pragma unroll
        for (int p = 0; p < 4; ++p) {
            int k = p * 8 + (tid >> 5);
            int n = (tid & 31) * 4;
            float4 v = *(const float4*)(W + (size_t)(k0 + k) * 128 + n);
            Bs[n + 0][k] = (f16)v.x; Bs[n + 1][k] = (f16)v.y;
            Bs[n + 2][k] = (f16)v.z; Bs[n + 3][k] = (f16)v.w;
        }
        __syncthreads();
        int kq = (l >> 4) * 8;
        f16x8 a[4], b[4];
        #pragma unroll
        for (int i = 0; i < 4; ++i) a[i] = *(const f16x8*)(&As[wm * 64 + i * 16 + (l & 15)][kq]);
        #pragma unroll
        for (int j = 0; j < 4; ++j) b[j] = *(const f16x8*)(&Bs[wn * 64 + j * 16 + (l & 15)][kq]);
        #pragma unroll
        for (int i = 0; i < 4; ++i)
            #pragma unroll
            for (int j = 0; j < 4; ++j)
                acc[i][j] = __builtin_amdgcn_mfma_f32_16x16x32_f16(a[i], b[j], acc[i][j], 0, 0, 0);
    }
    int lr = (l >> 4) * 4, lc = l & 15;
    #pragma unroll
    for (int i = 0; i < 4; ++i) {
        #pragma unroll
        for (int j = 0; j < 4; ++j) {
            int gcol = wn * 64 + j * 16 + lc;
            float bia = bias[gcol];
            #pragma unroll
            for (int q = 0; q < 4; ++q) {
                int grow = m0 + wm * 64 + i * 16 + lr + q;
                out[(size_t)grow * 128 + gcol] = acc[i][j][q] + bia;
            }
        }
    }
}

// ---------------- recurrent bidirectional GRU layer (XCD-self-organized) ----------------
// Grid 256 = CU count; 99KB LDS forces 1 block/CU => every XCD hosts exactly 32
// blocks. Blocks read HW_REG_XCC_ID and self-organize: chain = xcd (0..3, others
// exit), cg = atomic rank within xcd. Chains are therefore XCD-local BY
// CONSTRUCTION. Fast mode (plain stores -> shared XCD L2; batched sc0 asm loads)
// is gated by a sound two-round staleness probe + chain-wide vote; any anomaly
// falls back to the bit-exact r10 agent/L3 path. Per-block work/geometry = r10.
__launch_bounds__(256)
__global__ void gru_layer(
    const f16* __restrict__ proj_fw, const f16* __restrict__ proj_bw,
    const float* __restrict__ Wgh_fw, const float* __restrict__ Wgh_bw,
    const float* __restrict__ Wch_fw, const float* __restrict__ Wch_bw,
    const float* __restrict__ h0_fw, const float* __restrict__ h0_bw,
    f16* __restrict__ h16, f16* __restrict__ rh16, float* __restrict__ u32,
    f16* __restrict__ y, float* __restrict__ st_fw, float* __restrict__ st_bw,
    unsigned* __restrict__ ctrl)
{
    extern __shared__ f16 smem[];
    f16* stg    = smem;             // [16][1032]
    f16* Wc_lds = smem + 16 * 1032; // [32][1032]
    __shared__ int s_c, s_cg, s_ok;

    int tid = threadIdx.x;
    unsigned* regc = ctrl;          // 8 counters x 64B stride

    // ---- self-organized registration: chain = XCD id, cg = rank within XCD ----
    if (tid == 0) {
        unsigned xcc;
        asm volatile("s_getreg_b32 %0, hwreg(HW_REG_XCC_ID)" : "=s"(xcc));
        xcc &= 7u;
        unsigned rk = __hip_atomic_fetch_add(&regc[xcc * 16], 1u,
                                             __ATOMIC_RELAXED, __HIP_MEMORY_SCOPE_AGENT);
        int c = -1;
        if (xcc < 4u && rk < 32u) {
            int it = 0;   // wait until my chain is fully populated (32 members)
            while (__hip_atomic_load(&regc[xcc * 16], __ATOMIC_RELAXED,
                                     __HIP_MEMORY_SCOPE_AGENT) < 32u) {
                if (++it > (1 << 14)) break;
            }
            c = (int)xcc;
        }
        s_c = c; s_cg = (int)rk;
    }
    barsync();
    int c = s_c;
    if (c < 0) return;              // blocks on XCDs 4-7 (and overflow) exit
    int cg = s_cg;

    int dir = c >> 1, rh_i = c & 1;
    int R0  = rh_i * 16;
    int gcb = cg * 64;
    int ccb = cg * 32;

    const f16*  proj = dir ? proj_bw : proj_fw;
    const float* Wgh = dir ? Wgh_bw : Wgh_fw;
    const float* Wch = dir ? Wch_bw : Wch_fw;
    const float* h0  = dir ? h0_bw  : h0_fw;
    f16*   h16d  = h16  + dir * (NB * NU);
    f16*   rh16d = rh16 + dir * (NB * NU);
    float* u32d  = u32  + dir * (NB * NU);
    unsigned* cbase = ctrl + 128 + c * 2048;
    unsigned* fF    = cbase;          // 32 fast flags x 64B stride
    unsigned* fS    = cbase + 512;    // 32 slow flags
    unsigned* chk   = cbase + 1024;   // 32 probe slots
    unsigned* vote  = cbase + 1536;   // 32 vote slots

    const f16* hsrc  = h16d  + (size_t)R0 * NU;
    const f16* rhsrc = rh16d + (size_t)R0 * NU;

    int w = tid >> 6, l = tid & 63;
    int lc = l & 15, lr = (l >> 4) * 4, kq = (l >> 4) * 8;

    // ---- Wc slice (32 cols) into LDS ----
    {
        int j2 = tid & 31;
        for (int k = tid >> 5; k < NU; k += 8)
            Wc_lds[j2 * 1032 + k] = (f16)Wch[(size_t)k * 1024 + ccb + j2];
    }

    // ---- Wg fragments -> registers ----
    f16x8 wgf[32];
    {
        int col = gcb + w * 16 + lc;
        #pragma unroll
        for (int kt = 0; kt < 32; ++kt) {
            f16x8 t;
            #pragma unroll
            for (int e = 0; e < 8; ++e)
                t[e] = (f16)Wgh[(size_t)(kt * 32 + kq + e) * 2048 + col];
            wgf[kt] = t;
        }
    }

    // ---- init h (agent stores; disjoint slices) ----
    {
        int base2 = (rh_i * 32 + cg) * 512;
        for (int i = tid; i < 512; i += 256)
            cstore16(h16d + base2 + i, (f16)h0[base2 + i]);
    }
    f32x4 hreg = {};
    if (w < 2) {
        #pragma unroll
        for (int q = 0; q < 4; ++q)
            hreg[q] = h0[(size_t)(R0 + lr + q) * NU + ccb + w * 16 + lc];
    }

    int gc  = gcb + w * 16 + lc;           // gate col (this wave)
    int cc  = ccb + (w & 1) * 16 + lc;     // cand col (waves 0-1)
    int cc2 = 2048 + cc;
    bool rblk = (cg < 16);                 // block-uniform

    // ---- prefetch step-0 proj operands ----
    f16 pg[4], pc[4];
    {
        int td0 = dir ? (NT - 1) : 0;
        const f16* pr = proj + (size_t)td0 * NB * 3072;
        #pragma unroll
        for (int q = 0; q < 4; ++q) {
            pg[q] = pr[(size_t)(R0 + lr + q) * 3072 + gc];
            pc[q] = pr[(size_t)(R0 + lr + q) * 3072 + cc2];
        }
    }

    // ---- two-round staleness probe (slow/agent barriers), then chain vote ----
    unsigned bc = 0;
    if (tid == 0)
        st_plain_u32(chk + cg * 16, 0xA5000000u | ((unsigned)c << 8) | (unsigned)cg);
    ++bc; gbarx<false>(fF, fS, cg, bc);    // drains h init + token A
    int okA = 1, okB = 1;
    if (tid < 64) {
        unsigned v = ld_sc0_wait(chk + (tid & 31) * 16);   // seeds L2/L1-bypass path
        okA = __all(v == (0xA5000000u | ((unsigned)c << 8) | (unsigned)(tid & 31)));
    }
    if (tid == 0)
        st_plain_u32(chk + cg * 16, 0x5A000000u | ((unsigned)c << 8) | (unsigned)cg);
    ++bc; gbarx<false>(fF, fS, cg, bc);
    if (tid < 64) {
        unsigned v = ld_sc0_wait(chk + (tid & 31) * 16);   // re-read: stale?
        okB = __all(v == (0x5A000000u | ((unsigned)c << 8) | (unsigned)(tid & 31)));
    }
    if (tid == 0)
        __hip_atomic_store(vote + cg * 16, (okA && okB) ? 2u : 1u,
                           __ATOMIC_RELAXED, __HIP_MEMORY_SCOPE_AGENT);
    ++bc; gbarx<false>(fF, fS, cg, bc);
    if (tid < 64) {
        unsigned v = __hip_atomic_load(vote + (tid & 31) * 16, __ATOMIC_RELAXED,
                                       __HIP_MEMORY_SCOPE_AGENT);
        int ok = __all(v == 2u);
        if (tid == 0) s_ok = ok;
    }
    barsync();
    int fastmode = s_ok;

    auto run = [&](auto tag) {
        constexpr bool F = decltype(tag)::value;
        for (int tl = 0; tl < NT; ++tl) {
            int td = dir ? (NT - 1 - tl) : tl;

            // ---- stage h (16 rows) -> LDS ----
            if constexpr (F) stage16f(hsrc, stg, tid);
            else             stage16s(hsrc, stg, tid);
            asm volatile("s_waitcnt lgkmcnt(0)" ::: "memory");
            __builtin_amdgcn_sched_barrier(0);
            barsync();

            // ---- phase A: ru = sigmoid(proj_g + h @ Wg_h) ----
            {
                const f16* ap = &stg[lc * 1032 + kq];
                f32x4 acc0 = {}, acc1 = {};
                #pragma unroll
                for (int kt = 0; kt < 32; kt += 2) {
                    f16x8 a0 = *(const f16x8*)(ap + kt * 32);
                    f16x8 a1 = *(const f16x8*)(ap + (kt + 1) * 32);
                    acc0 = __builtin_amdgcn_mfma_f32_16x16x32_f16(a0, wgf[kt], acc0, 0, 0, 0);
                    acc1 = __builtin_amdgcn_mfma_f32_16x16x32_f16(a1, wgf[kt + 1], acc1, 0, 0, 0);
                }
                f32x4 acc = acc0 + acc1;
                #pragma unroll
                for (int q = 0; q < 4; ++q) {
                    int br = lr + q;           // local row
                    float pre = acc[q] + (float)pg[q];
                    float sg = 1.f / (1.f + __expf(-pre));
                    if (rblk) {
                        float hv = (float)stg[br * 1032 + gc];
                        f16 v = (f16)(sg * hv);
                        if constexpr (F) rh16d[(size_t)(R0 + br) * NU + gc] = v;
                        else             cstore16(rh16d + (size_t)(R0 + br) * NU + gc, v);
                    } else {
                        if constexpr (F) u32d[(size_t)(R0 + br) * NU + gc - NU] = sg;
                        else             cstoref(u32d + (size_t)(R0 + br) * NU + gc - NU, sg);
                    }
                }
            }
            ++bc;
            gbarx<F>(fF, fS, cg, bc);   // barrier #1: rh/u published

            // ---- u loads (own chain; written by u-blocks) ----
            float uu[4];
            if constexpr (F) {
                const float* p0 = (w < 2) ? u32d + (size_t)(R0 + lr + 0) * NU + cc : u32d;
                const float* p1 = (w < 2) ? u32d + (size_t)(R0 + lr + 1) * NU + cc : u32d;
                const float* p2 = (w < 2) ? u32d + (size_t)(R0 + lr + 2) * NU + cc : u32d;
                const float* p3 = (w < 2) ? u32d + (size_t)(R0 + lr + 3) * NU + cc : u32d;
                ld4f_sc0(p0, p1, p2, p3, uu);
            } else {
                if (w < 2) {
                    #pragma unroll
                    for (int q = 0; q < 4; ++q)
                        uu[q] = cloadf(u32d + (size_t)(R0 + lr + q) * NU + cc);
                }
            }

            // ---- stage rh (16 rows) -> LDS ----
            if constexpr (F) stage16f(rhsrc, stg, tid);
            else             stage16s(rhsrc, stg, tid);
            asm volatile("s_waitcnt lgkmcnt(0)" ::: "memory");
            __builtin_amdgcn_sched_barrier(0);
            barsync();

            // ---- phase B: c = tanh(proj_c + (r*h) @ Wc_h); h = u*h + (1-u)*c ----
            if (w < 2) {
                const f16* ap = &stg[lc * 1032 + kq];
                const f16* bptr = Wc_lds + ((w & 1) * 16 + lc) * 1032 + kq;
                f32x4 acc0 = {}, acc1 = {};
                #pragma unroll
                for (int kt = 0; kt < 32; kt += 2) {
                    f16x8 a0 = *(const f16x8*)(ap + kt * 32);
                    f16x8 a1 = *(const f16x8*)(ap + (kt + 1) * 32);
                    f16x8 b0 = *(const f16x8*)(bptr + kt * 32);
                    f16x8 b1 = *(const f16x8*)(bptr + kt * 32 + 32);
                    acc0 = __builtin_amdgcn_mfma_f32_16x16x32_f16(a0, b0, acc0, 0, 0, 0);
                    acc1 = __builtin_amdgcn_mfma_f32_16x16x32_f16(a1, b1, acc1, 0, 0, 0);
                }
                f32x4 acc = acc0 + acc1;
                #pragma unroll
                for (int q = 0; q < 4; ++q) {
                    int br = R0 + lr + q;      // global row
                    float pre = acc[q] + (float)pc[q];
                    float e2 = __expf(2.f * pre);
                    float cv = 1.f - 2.f / (e2 + 1.f);   // tanh(pre)
                    float hn = uu[q] * hreg[q] + (1.f - uu[q]) * cv;
                    hreg[q] = hn;
                    f16 hv = (f16)hn;
                    if constexpr (F) h16d[(size_t)br * NU + cc] = hv;
                    else             cstore16(h16d + (size_t)br * NU + cc, hv);
                }
            }
            ++bc;
            // barrier #2 inline: drain h16, arrive, window work, wait
            asm volatile("s_waitcnt vmcnt(0)" ::: "memory");
            barsync();
            arrivex<F>(fF, fS, cg, bc);
            // window: y / final-state stores
            if (w < 2) {
                #pragma unroll
                for (int q = 0; q < 4; ++q) {
                    int br = R0 + lr + q;
                    y[(size_t)(td * NB + br) * 2048 + dir * NU + cc] = (f16)hreg[q];
                    if (tl == NT - 1)
                        (dir ? st_bw : st_fw)[(size_t)br * NU + cc] = hreg[q];
                }
            }
            // window: prefetch next step's proj operands
            if (tl + 1 < NT) {
                int tdn = dir ? (NT - 2 - tl) : (tl + 1);
                const f16* pr = proj + (size_t)tdn * NB * 3072;
                #pragma unroll
                for (int q = 0; q < 4; ++q) {
                    pg[q] = pr[(size_t)(R0 + lr + q) * 3072 + gc];
                    pc[q] = pr[(size_t)(R0 + lr + q) * 3072 + cc2];
                }
            }
            gwaitx<F>(fF, fS, bc);
            barsync();
        }
    };
    if (fastmode) run(BoolT<true>{});
    else          run(BoolT<false>{});
}

// ---------------- host launch ----------------
extern "C" void kernel_launch(void* const* d_in, const int* in_sizes, int n_in,
                              void* d_out, int out_size, void* d_ws, size_t ws_size,
                              hipStream_t stream) {
    const int*   x   = (const int*)  d_in[0];
    const float* emb = (const float*)d_in[1];
    const float* fcW = (const float*)d_in[2];
    const float* fcb = (const float*)d_in[3];
    float* out = (float*)d_out;

    char* ws = (char*)d_ws;
    size_t off = 0;
    f16* seq0   = (f16*)(ws + off); off += (size_t)8192 * 256 * 2;
    f16* ybuf0  = (f16*)(ws + off); off += (size_t)8192 * 2048 * 2;
    f16* ybuf1  = (f16*)(ws + off); off += (size_t)8192 * 2048 * 2;
    f16* projfw = (f16*)(ws + off); off += (size_t)8192 * 3072 * 2;
    f16* projbw = (f16*)(ws + off); off += (size_t)8192 * 3072 * 2;
    f16*   h16  = (f16*)(ws + off);   off += 2 * 32 * 1024 * 2;
    f16*   rh16 = (f16*)(ws + off);   off += 2 * 32 * 1024 * 2;
    float* u32  = (float*)(ws + off); off += 2 * 32 * 1024 * 4;
    unsigned* ctrl = (unsigned*)(ws + off); off += 3 * 49152;  // 12288 u32 / layer
    // per-layer-reused f16 transposed-weight slot (max-layer sizes, K2=3072)
    f16* WgT_fw = (f16*)(ws + off); off += (size_t)2048 * 3072 * 2;
    f16* WgT_bw = (f16*)(ws + off); off += (size_t)2048 * 3072 * 2;
    f16* WcT_fw = (f16*)(ws + off); off += (size_t)1024 * 3072 * 2;
    f16* WcT_bw = (f16*)(ws + off); off += (size_t)1024 * 3072 * 2;
    bool cvt = (ws_size >= off);   // fall back to f32 gemm if slot doesn't fit

    hipFuncSetAttribute((const void*)gru_layer,
                        hipFuncAttributeMaxDynamicSharedMemorySize, 99072);

    hipMemsetAsync(ctrl, 0, 3 * 49152, stream);
    embed_kernel<<<dim3(8192), dim3(256), 0, stream>>>(x, emb, seq0);

    const f16* lin = seq0; int lda = 256, K = 256;
    f16* ybufs[2] = {ybuf0, ybuf1};
    for (int l = 0; l < 3; ++l) {
        const float* Wg_fw = (const float*)d_in[4 + l * 10 + 0];
        const float* bg_fw = (const float*)d_in[4 + l * 10 + 1];
        const float* Wc_fw = (const float*)d_in[4 + l * 10 + 2];
        const float* bc_fw = (const float*)d_in[4 + l * 10 + 3];
        const float* h0_fw = (const float*)d_in[4 + l * 10 + 4];
        const float* Wg_bw = (const float*)d_in[4 + l * 10 + 5];
        const float* bg_bw = (const float*)d_in[4 + l * 10 + 6];
        const float* Wc_bw = (const float*)d_in[4 + l * 10 + 7];
        const float* bc_bw = (const float*)d_in[4 + l * 10 + 8];
        const float* h0_bw = (const float*)d_in[4 + l * 10 + 9];
        int din = (l == 0) ? 256 : 2048;
        int K2 = din + 1024;

        if (cvt) {
            wconv<<<dim3(K2 / 32, 64, 2), dim3(256), 0, stream>>>(Wg_fw, Wc_fw, WgT_fw, WcT_fw, K2);
            wconv<<<dim3(K2 / 32, 64, 2), dim3(256), 0, stream>>>(Wg_bw, Wc_bw, WgT_bw, WcT_bw, K2);
            gemm_projT<<<dim3(64, 24), dim3(256), 0, stream>>>(lin, lda, K, WgT_fw, WcT_fw, K2, bg_fw, bc_fw, projfw);
            gemm_projT<<<dim3(64, 24), dim3(256), 0, stream>>>(lin, lda, K, WgT_bw, WcT_bw, K2, bg_bw, bc_bw, projbw);
        } else {
            gemm_proj<<<dim3(64, 24), dim3(256), 0, stream>>>(lin, lda, K, Wg_fw, Wc_fw, bg_fw, bc_fw, projfw);
            gemm_proj<<<dim3(64, 24), dim3(256), 0, stream>>>(lin, lda, K, Wg_bw, Wc_bw, bg_bw, bc_bw, projbw);
        }

        const float* Wgh_fw = Wg_fw + (size_t)din * 2048;
        const float* Wgh_bw = Wg_bw + (size_t)din * 2048;
        const float* Wch_fw = Wc_fw + (size_t)din * 1024;
        const float* Wch_bw = Wc_bw + (size_t)din * 1024;
        f16* yout = ybufs[l & 1];
        float* stfw = out + 1048576 + l * 32768;
        float* stbw = out + 1048576 + 98304 + l * 32768;
        unsigned* cnt = ctrl + l * 12288;

        gru_layer<<<dim3(256), dim3(256), 99072, stream>>>(
            projfw, projbw, Wgh_fw, Wgh_bw, Wch_fw, Wch_bw, h0_fw, h0_bw,
            h16, rh16, u32, yout, stfw, stbw, cnt);
        lin = yout; lda = 2048; K = 2048;
    }

    gemm_fc<<<dim3(64), dim3(256), 0, stream>>>(ybufs[0], fcW, fcb, out);
}

// Round 15
// 5812.696 us; speedup vs baseline: 4.1722x; 1.9834x over previous
//
#include <hip/hip_runtime.h>

typedef _Float16 f16;
typedef _Float16 f16x4 __attribute__((ext_vector_type(4)));
typedef _Float16 f16x8 __attribute__((ext_vector_type(8)));
typedef float f32x4 __attribute__((ext_vector_type(4)));

#define NB 32
#define NT 256
#define NE 256
#define NU 1024
#define NV 128

#define MEMF() asm volatile("" ::: "memory")

// ---------- agent-coherent (cross-XCD, L3-level) load/store helpers ----------
__device__ __forceinline__ unsigned long long cload64(const f16* p) {
    return __hip_atomic_load((const unsigned long long*)p, __ATOMIC_RELAXED,
                             __HIP_MEMORY_SCOPE_AGENT);
}
__device__ __forceinline__ float cloadf(const float* p) {
    return __hip_atomic_load(p, __ATOMIC_RELAXED, __HIP_MEMORY_SCOPE_AGENT);
}
__device__ __forceinline__ void cstoref(float* p, float v) {
    __hip_atomic_store(p, v, __ATOMIC_RELAXED, __HIP_MEMORY_SCOPE_AGENT);
}
__device__ __forceinline__ void cstore16(f16* p, f16 v) {
    __hip_atomic_store((unsigned short*)p, __builtin_bit_cast(unsigned short, v),
                       __ATOMIC_RELAXED, __HIP_MEMORY_SCOPE_AGENT);
}

__device__ __forceinline__ void barsync() {
    MEMF();
    __builtin_amdgcn_s_barrier();
    MEMF();
}

// wave-0 vector poll over a 32-block domain: lane l watches flag (l&31).
__device__ __forceinline__ void gwait(const unsigned* flagd, unsigned target) {
    if (threadIdx.x < 64) {
        int it = 0;
        for (;;) {
            unsigned v = __hip_atomic_load(&flagd[(threadIdx.x & 31) * 16],
                                           __ATOMIC_RELAXED, __HIP_MEMORY_SCOPE_AGENT);
            if (__all(v >= target)) break;
            if (++it > (1 << 16)) break;  // failsafe: fail visibly, don't hang
        }
    }
}

// full barrier over the block's 32-member domain
__device__ __forceinline__ void gbar(unsigned* flagd, int cg, unsigned target) {
    asm volatile("s_waitcnt vmcnt(0)" ::: "memory");
    barsync();
    if (threadIdx.x == 0)
        __hip_atomic_store(&flagd[cg * 16], target, __ATOMIC_RELAXED,
                           __HIP_MEMORY_SCOPE_AGENT);
    gwait(flagd, target);
    barsync();
}

// stage 16 rows x 1024 f16 from agent-coherent global into LDS (pitch 1032).
// All 16 loads issued before any LDS write -> one L3 round trip.
__device__ __forceinline__ void stage16(const f16* __restrict__ src,
                                        f16* __restrict__ stg, int tid) {
    unsigned long long a[16];
    #pragma unroll
    for (int i = 0; i < 16; ++i)
        a[i] = cload64(src + i * NU + tid * 4);
    MEMF();
    #pragma unroll
    for (int i = 0; i < 16; ++i)
        *(f16x4*)(&stg[i * 1032 + tid * 4]) = __builtin_bit_cast(f16x4, a[i]);
}

// ---------------- embedding ----------------
__global__ void embed_kernel(const int* __restrict__ x, const float* __restrict__ emb,
                             f16* __restrict__ seq0) {
    int row = blockIdx.x;           // t*NB + b
    int t = row >> 5, b = row & 31;
    int e = threadIdx.x;
    int idx = x[b * NT + t];
    seq0[row * NE + e] = (f16)emb[idx * NE + e];
}

// ---------------- weight transpose+convert: WT[n][k] (f16) = W[k][n] (f32) ----------------
__global__ void wconv(const float* __restrict__ Wg, const float* __restrict__ Wc,
                      f16* __restrict__ WgT, f16* __restrict__ WcT, int K2) {
    __shared__ float tile[32][33];
    int mat = blockIdx.z & 1;
    const float* in = mat ? Wc : Wg;
    f16* outp = mat ? WcT : WgT;
    int N = mat ? 1024 : 2048;
    int by = blockIdx.y;
    if (by * 32 >= N) return;
    int k0 = blockIdx.x * 32, n0 = by * 32;
    int tx = threadIdx.x & 31, ty = threadIdx.x >> 5;  // 32 x 8
    #pragma unroll
    for (int i = 0; i < 4; ++i) {
        int r = ty * 4 + i;
        tile[r][tx] = in[(size_t)(k0 + r) * N + n0 + tx];
    }
    __syncthreads();
    #pragma unroll
    for (int i = 0; i < 4; ++i) {
        int rn = ty * 4 + i;
        outp[(size_t)(n0 + rn) * K2 + k0 + tx] = (f16)tile[tx][rn];
    }
}

// ---------------- input-projection GEMM, f16 transposed-weight edition ----------------
__launch_bounds__(256)
__global__ void gemm_projT(const f16* __restrict__ A, int lda, int K,
                           const f16* __restrict__ WgT, const f16* __restrict__ WcT, int K2,
                           const float* __restrict__ bg, const float* __restrict__ bc,
                           f16* __restrict__ proj) {
    __shared__ f16 As[128][40];
    __shared__ f16 Bs[128][40];
    int cb = blockIdx.y;
    const f16* Bsrc; int outcol; const float* bias;
    if (cb < 16) { Bsrc = WgT + (size_t)cb * 128 * K2; outcol = cb * 128; bias = bg + cb * 128; }
    else { Bsrc = WcT + (size_t)(cb - 16) * 128 * K2; outcol = 2048 + (cb - 16) * 128; bias = bc + (cb - 16) * 128; }
    int m0 = blockIdx.x * 128;
    int tid = threadIdx.x;
    int w = tid >> 6, l = tid & 63;
    int wm = w & 1, wn = w >> 1;
    f32x4 acc[4][4] = {};
    for (int k0 = 0; k0 < K; k0 += 32) {
        __syncthreads();
        #pragma unroll
        for (int p = 0; p < 2; ++p) {
            int e = (p * 256 + tid) * 8;
            int r = e >> 5, kq = e & 31;
            f16x8 v = *(const f16x8*)(A + (size_t)(m0 + r) * lda + k0 + kq);
            *(f16x8*)(&As[r][kq]) = v;
        }
        #pragma unroll
        for (int p = 0; p < 2; ++p) {
            int e = (p * 256 + tid) * 8;
            int r = e >> 5, kq = e & 31;
            f16x8 v = *(const f16x8*)(Bsrc + (size_t)r * K2 + k0 + kq);
            *(f16x8*)(&Bs[r][kq]) = v;
        }
        __syncthreads();
        int kq = (l >> 4) * 8;
        f16x8 a[4], b[4];
        #pragma unroll
        for (int i = 0; i < 4; ++i) a[i] = *(const f16x8*)(&As[wm * 64 + i * 16 + (l & 15)][kq]);
        #pragma unroll
        for (int j = 0; j < 4; ++j) b[j] = *(const f16x8*)(&Bs[wn * 64 + j * 16 + (l & 15)][kq]);
        #pragma unroll
        for (int i = 0; i < 4; ++i)
            #pragma unroll
            for (int j = 0; j < 4; ++j)
                acc[i][j] = __builtin_amdgcn_mfma_f32_16x16x32_f16(a[i], b[j], acc[i][j], 0, 0, 0);
    }
    int lr = (l >> 4) * 4, lc = l & 15;
    #pragma unroll
    for (int i = 0; i < 4; ++i) {
        #pragma unroll
        for (int j = 0; j < 4; ++j) {
            int gcol = wn * 64 + j * 16 + lc;
            float bia = bias[gcol];
            #pragma unroll
            for (int q = 0; q < 4; ++q) {
                int grow = m0 + wm * 64 + i * 16 + lr + q;
                proj[(size_t)grow * 3072 + outcol + gcol] = (f16)(acc[i][j][q] + bia);
            }
        }
    }
}

// ---------------- input-projection GEMM (fallback, f32 weights) ----------------
__launch_bounds__(256)
__global__ void gemm_proj(const f16* __restrict__ A, int lda, int K,
                          const float* __restrict__ Wg, const float* __restrict__ Wc,
                          const float* __restrict__ bg, const float* __restrict__ bc,
                          f16* __restrict__ proj) {
    __shared__ f16 As[128][40];
    __shared__ f16 Bs[128][40];
    int cb = blockIdx.y;
    const float* Bsrc; int ldb, outcol; const float* bias;
    if (cb < 16) { Bsrc = Wg + cb * 128; ldb = 2 * NU; outcol = cb * 128; bias = bg + cb * 128; }
    else { Bsrc = Wc + (cb - 16) * 128; ldb = NU; outcol = 2 * NU + (cb - 16) * 128; bias = bc + (cb - 16) * 128; }
    int m0 = blockIdx.x * 128;
    int tid = threadIdx.x;
    int w = tid >> 6, l = tid & 63;
    int wm = w & 1, wn = w >> 1;
    f32x4 acc[4][4] = {};
    for (int k0 = 0; k0 < K; k0 += 32) {
        __syncthreads();
        #pragma unroll
        for (int p = 0; p < 2; ++p) {
            int e = (p * 256 + tid) * 8;
            int r = e >> 5, kq = e & 31;
            f16x8 v = *(const f16x8*)(A + (size_t)(m0 + r) * lda + k0 + kq);
            *(f16x8*)(&As[r][kq]) = v;
        }
        #pragma unroll
        for (int p = 0; p < 4; ++p) {
            int k = p * 8 + (tid >> 5);
            int n = (tid & 31) * 4;
            float4 v = *(const float4*)(Bsrc + (size_t)(k0 + k) * ldb + n);
            Bs[n + 0][k] = (f16)v.x; Bs[n + 1][k] = (f16)v.y;
            Bs[n + 2][k] = (f16)v.z; Bs[n + 3][k] = (f16)v.w;
        }
        __syncthreads();
        int kq = (l >> 4) * 8;
        f16x8 a[4], b[4];
        #pragma unroll
        for (int i = 0; i < 4; ++i) a[i] = *(const f16x8*)(&As[wm * 64 + i * 16 + (l & 15)][kq]);
        #pragma unroll
        for (int j = 0; j < 4; ++j) b[j] = *(const f16x8*)(&Bs[wn * 64 + j * 16 + (l & 15)][kq]);
        #pragma unroll
        for (int i = 0; i < 4; ++i)
            #pragma unroll
            for (int j = 0; j < 4; ++j)
                acc[i][j] = __builtin_amdgcn_mfma_f32_16x16x32_f16(a[i], b[j], acc[i][j], 0, 0, 0);
    }
    int lr = (l >> 4) * 4, lc = l & 15;
    #pragma unroll
    for (int i = 0; i < 4; ++i) {
        #pragma unroll
        for (int j = 0; j < 4; ++j) {
            int gcol = wn * 64 + j * 16 + lc;
            float bia = bias[gcol];
            #pragma unroll
            for (int q = 0; q < 4; ++q) {
                int grow = m0 + wm * 64 + i * 16 + lr + q;
                proj[(size_t)grow * 3072 + outcol + gcol] = (f16)(acc[i][j][q] + bia);
            }
        }
    }
}

// ---------------- final FC ----------------
__launch_bounds__(256)
__global__ void gemm_fc(const f16* __restrict__ y, const float* __restrict__ W,
                        const float* __restrict__ bias, float* __restrict__ out) {
    __shared__ f16 As[128][40];
    __shared__ f16 Bs[128][40];
    int m0 = blockIdx.x * 128;
    int tid = threadIdx.x;
    int w = tid >> 6, l = tid & 63;
    int wm = w & 1, wn = w >> 1;
    f32x4 acc[4][4] = {};
    for (int k0 = 0; k0 < 2048; k0 += 32) {
        __syncthreads();
        #pragma unroll
        for (int p = 0; p < 2; ++p) {
            int e = (p * 256 + tid) * 8;
            int r = e >> 5, kq = e & 31;
            int grow = m0 + r;                 // row = b*256 + t
            int b = grow >> 8, t = grow & 255;
            f16x8 v = *(const f16x8*)(y + (size_t)(t * 32 + b) * 2048 + k0 + kq);
            *(f16x8*)(&As[r][kq]) = v;
        }
        #pragma unroll
        for (int p = 0; p < 4; ++p) {
            int k = p * 8 + (tid >> 5);
            int n = (tid & 31) * 4;
            float4 v = *(const float4*)(W + (size_t)(k0 + k) * 128 + n);
            Bs[n + 0][k] = (f16)v.x; Bs[n + 1][k] = (f16)v.y;
            Bs[n + 2][k] = (f16)v.z; Bs[n + 3][k] = (f16)v.w;
        }
        __syncthreads();
        int kq = (l >> 4) * 8;
        f16x8 a[4], b[4];
        #pragma unroll
        for (int i = 0; i < 4; ++i) a[i] = *(const f16x8*)(&As[wm * 64 + i * 16 + (l & 15)][kq]);
        #pragma unroll
        for (int j = 0; j < 4; ++j) b[j] = *(const f16x8*)(&Bs[wn * 64 + j * 16 + (l & 15)][kq]);
        #pragma unroll
        for (int i = 0; i < 4; ++i)
            #pragma unroll
            for (int j = 0; j < 4; ++j)
                acc[i][j] = __builtin_amdgcn_mfma_f32_16x16x32_f16(a[i], b[j], acc[i][j], 0, 0, 0);
    }
    int lr = (l >> 4) * 4, lc = l & 15;
    #pragma unroll
    for (int i = 0; i < 4; ++i) {
        #pragma unroll
        for (int j = 0; j < 4; ++j) {
            int gcol = wn * 64 + j * 16 + lc;
            float bia = bias[gcol];
            #pragma unroll
            for (int q = 0; q < 4; ++q) {
                int grow = m0 + wm * 64 + i * 16 + lr + q;
                out[(size_t)grow * 128 + gcol] = acc[i][j][q] + bia;
            }
        }
    }
}

// ---------------- recurrent bidirectional GRU layer (r10-proven) ----------------
// Row-split: 128 blocks x 256 threads. Block = (dir, rowhalf rh_i, colgroup cg).
// Each (dir,rowhalf) is an INDEPENDENT 16-row chain with its own 32-block barrier
// domain (batch rows don't couple in a GRU). Per block: 64 gate cols (4 waves,
// wgf[32] in regs) + 32 cand cols (waves 0-1, Wc in LDS). LDS: stage[16][1032]
// (33KB) + Wc[32][1032] (66KB) = 99072B. Normal launch. All cross-block traffic
// agent/L3 (r11-r13 refuted the XCD-local sc0/volatile paths).
__launch_bounds__(256)
__global__ void gru_layer(
    const f16* __restrict__ proj_fw, const f16* __restrict__ proj_bw,
    const float* __restrict__ Wgh_fw, const float* __restrict__ Wgh_bw,
    const float* __restrict__ Wch_fw, const float* __restrict__ Wch_bw,
    const float* __restrict__ h0_fw, const float* __restrict__ h0_bw,
    f16* __restrict__ h16, f16* __restrict__ rh16, float* __restrict__ u32,
    f16* __restrict__ y, float* __restrict__ st_fw, float* __restrict__ st_bw,
    unsigned* __restrict__ cnt)
{
    extern __shared__ f16 smem[];
    f16* stg    = smem;             // [16][1032]
    f16* Wc_lds = smem + 16 * 1032; // [32][1032]

    int bid = blockIdx.x, tid = threadIdx.x;
    int dir = bid >> 6, lb = bid & 63;
    int rh_i = lb >> 5;          // row half (rows R0..R0+15)
    int cg   = lb & 31;          // col group
    int R0   = rh_i * 16;
    int gcb  = cg * 64;          // gate col base (0..1983)
    int ccb  = cg * 32;          // cand col base (0..991)

    const f16*  proj = dir ? proj_bw : proj_fw;
    const float* Wgh = dir ? Wgh_bw : Wgh_fw;
    const float* Wch = dir ? Wch_bw : Wch_fw;
    const float* h0  = dir ? h0_bw  : h0_fw;
    f16*   h16d  = h16  + dir * (NB * NU);
    f16*   rh16d = rh16 + dir * (NB * NU);
    float* u32d  = u32  + dir * (NB * NU);
    unsigned* flagd = cnt + (dir * 2 + rh_i) * 1024;  // 32 flags x 64B stride

    const f16* hsrc  = h16d  + (size_t)R0 * NU;
    const f16* rhsrc = rh16d + (size_t)R0 * NU;

    int w = tid >> 6, l = tid & 63;
    int lc = l & 15, lr = (l >> 4) * 4, kq = (l >> 4) * 8;

    // ---- Wc slice (32 cols) into LDS ----
    {
        int j2 = tid & 31;
        for (int k = tid >> 5; k < NU; k += 8)
            Wc_lds[j2 * 1032 + k] = (f16)Wch[(size_t)k * 1024 + ccb + j2];
    }

    // ---- Wg fragments -> registers (wave w covers col tile w of 4) ----
    f16x8 wgf[32];
    {
        int col = gcb + w * 16 + lc;
        #pragma unroll
        for (int kt = 0; kt < 32; ++kt) {
            f16x8 t;
            #pragma unroll
            for (int e = 0; e < 8; ++e)
                t[e] = (f16)Wgh[(size_t)(kt * 32 + kq + e) * 2048 + col];
            wgf[kt] = t;
        }
    }

    // ---- init h: publish h16 (disjoint 512-elem slices; domain-local rows) ----
    {
        int base = lb * 512;
        for (int i = tid; i < 512; i += 256)
            cstore16(h16d + base + i, (f16)h0[base + i]);
    }
    // cand h in regs (waves 0-1: col tile w of 2)
    f32x4 hreg = {};
    if (w < 2) {
        #pragma unroll
        for (int q = 0; q < 4; ++q)
            hreg[q] = h0[(size_t)(R0 + lr + q) * NU + ccb + w * 16 + lc];
    }

    int gc  = gcb + w * 16 + lc;           // gate col (this wave)
    int cc  = ccb + (w & 1) * 16 + lc;     // cand col (waves 0-1)
    int cc2 = 2048 + cc;
    bool rblk = (cg < 16);                 // block-uniform

    // ---- prefetch step-0 proj operands ----
    f16 pg[4], pc[4];
    {
        int td0 = dir ? (NT - 1) : 0;
        const f16* pr = proj + (size_t)td0 * NB * 3072;
        #pragma unroll
        for (int q = 0; q < 4; ++q) {
            pg[q] = pr[(size_t)(R0 + lr + q) * 3072 + gc];
            pc[q] = pr[(size_t)(R0 + lr + q) * 3072 + cc2];
        }
    }

    unsigned bc = 1;
    gbar(flagd, cg, bc);

    for (int tl = 0; tl < NT; ++tl) {
        int td = dir ? (NT - 1 - tl) : tl;

        // ---- stage h (16 rows) -> LDS ----
        stage16(hsrc, stg, tid);
        asm volatile("s_waitcnt lgkmcnt(0)" ::: "memory");
        __builtin_amdgcn_sched_barrier(0);
        barsync();

        // ---- phase A: ru = sigmoid(proj_g + h @ Wg_h)  (all 4 waves) ----
        {
            const f16* ap = &stg[lc * 1032 + kq];
            f32x4 acc0 = {}, acc1 = {};
            #pragma unroll
            for (int kt = 0; kt < 32; kt += 2) {
                f16x8 a0 = *(const f16x8*)(ap + kt * 32);
                f16x8 a1 = *(const f16x8*)(ap + (kt + 1) * 32);
                acc0 = __builtin_amdgcn_mfma_f32_16x16x32_f16(a0, wgf[kt], acc0, 0, 0, 0);
                acc1 = __builtin_amdgcn_mfma_f32_16x16x32_f16(a1, wgf[kt + 1], acc1, 0, 0, 0);
            }
            f32x4 acc = acc0 + acc1;
            #pragma unroll
            for (int q = 0; q < 4; ++q) {
                int br = lr + q;           // local row
                float pre = acc[q] + (float)pg[q];
                float sg = 1.f / (1.f + __expf(-pre));
                if (rblk) {   // r-block: rh from staged h
                    float hv = (float)stg[br * 1032 + gc];
                    cstore16(rh16d + (size_t)(R0 + br) * NU + gc, (f16)(sg * hv));
                } else {      // u-block
                    cstoref(u32d + (size_t)(R0 + br) * NU + gc - NU, sg);
                }
            }
        }
        ++bc;
        gbar(flagd, cg, bc);   // barrier #1: rh/u published

        // ---- early u loads (overlap with rh stage) ----
        float uu[4];
        if (w < 2) {
            #pragma unroll
            for (int q = 0; q < 4; ++q)
                uu[q] = cloadf(u32d + (size_t)(R0 + lr + q) * NU + cc);
        }

        // ---- stage rh (16 rows) -> LDS ----
        stage16(rhsrc, stg, tid);
        asm volatile("s_waitcnt lgkmcnt(0)" ::: "memory");
        __builtin_amdgcn_sched_barrier(0);
        barsync();

        // ---- phase B: c = tanh(proj_c + (r*h) @ Wc_h); h = u*h + (1-u)*c ----
        if (w < 2) {
            const f16* ap = &stg[lc * 1032 + kq];
            const f16* bptr = Wc_lds + ((w & 1) * 16 + lc) * 1032 + kq;
            f32x4 acc0 = {}, acc1 = {};
            #pragma unroll
            for (int kt = 0; kt < 32; kt += 2) {
                f16x8 a0 = *(const f16x8*)(ap + kt * 32);
                f16x8 a1 = *(const f16x8*)(ap + (kt + 1) * 32);
                f16x8 b0 = *(const f16x8*)(bptr + kt * 32);
                f16x8 b1 = *(const f16x8*)(bptr + kt * 32 + 32);
                acc0 = __builtin_amdgcn_mfma_f32_16x16x32_f16(a0, b0, acc0, 0, 0, 0);
                acc1 = __builtin_amdgcn_mfma_f32_16x16x32_f16(a1, b1, acc1, 0, 0, 0);
            }
            f32x4 acc = acc0 + acc1;
            #pragma unroll
            for (int q = 0; q < 4; ++q) {
                int br = R0 + lr + q;      // global row
                float pre = acc[q] + (float)pc[q];
                float e2 = __expf(2.f * pre);
                float c = 1.f - 2.f / (e2 + 1.f);   // tanh(pre)
                float hn = uu[q] * hreg[q] + (1.f - uu[q]) * c;
                hreg[q] = hn;
                cstore16(h16d + (size_t)br * NU + cc, (f16)hn);
            }
        }
        ++bc;
        // barrier #2 inline: drain h16, arrive, then window work, then wait
        asm volatile("s_waitcnt vmcnt(0)" ::: "memory");
        barsync();
        if (tid == 0)
            __hip_atomic_store(&flagd[cg * 16], bc, __ATOMIC_RELAXED,
                               __HIP_MEMORY_SCOPE_AGENT);
        // window: y / final-state stores (not needed by other blocks)
        if (w < 2) {
            #pragma unroll
            for (int q = 0; q < 4; ++q) {
                int br = R0 + lr + q;
                y[(size_t)(td * NB + br) * 2048 + dir * NU + cc] = (f16)hreg[q];
                if (tl == NT - 1)
                    (dir ? st_bw : st_fw)[(size_t)br * NU + cc] = hreg[q];
            }
        }
        // window: prefetch next step's proj operands
        if (tl + 1 < NT) {
            int tdn = dir ? (NT - 2 - tl) : (tl + 1);
            const f16* pr = proj + (size_t)tdn * NB * 3072;
            #pragma unroll
            for (int q = 0; q < 4; ++q) {
                pg[q] = pr[(size_t)(R0 + lr + q) * 3072 + gc];
                pc[q] = pr[(size_t)(R0 + lr + q) * 3072 + cc2];
            }
        }
        gwait(flagd, bc);
        barsync();
    }
}

// ---------------- host launch ----------------
extern "C" void kernel_launch(void* const* d_in, const int* in_sizes, int n_in,
                              void* d_out, int out_size, void* d_ws, size_t ws_size,
                              hipStream_t stream) {
    const int*   x   = (const int*)  d_in[0];
    const float* emb = (const float*)d_in[1];
    const float* fcW = (const float*)d_in[2];
    const float* fcb = (const float*)d_in[3];
    float* out = (float*)d_out;

    char* ws = (char*)d_ws;
    size_t off = 0;
    f16* seq0   = (f16*)(ws + off); off += (size_t)8192 * 256 * 2;
    f16* ybuf0  = (f16*)(ws + off); off += (size_t)8192 * 2048 * 2;
    f16* ybuf1  = (f16*)(ws + off); off += (size_t)8192 * 2048 * 2;
    f16* projfw = (f16*)(ws + off); off += (size_t)8192 * 3072 * 2;
    f16* projbw = (f16*)(ws + off); off += (size_t)8192 * 3072 * 2;
    f16*   h16  = (f16*)(ws + off);   off += 2 * 32 * 1024 * 2;
    f16*   rh16 = (f16*)(ws + off);   off += 2 * 32 * 1024 * 2;
    float* u32  = (float*)(ws + off); off += 2 * 32 * 1024 * 4;
    unsigned* ctrl = (unsigned*)(ws + off); off += 3 * 16384;  // 3 layers x 4096 u32
    // per-layer-reused f16 transposed-weight slot (max-layer sizes, K2=3072)
    f16* WgT_fw = (f16*)(ws + off); off += (size_t)2048 * 3072 * 2;
    f16* WgT_bw = (f16*)(ws + off); off += (size_t)2048 * 3072 * 2;
    f16* WcT_fw = (f16*)(ws + off); off += (size_t)1024 * 3072 * 2;
    f16* WcT_bw = (f16*)(ws + off); off += (size_t)1024 * 3072 * 2;
    bool cvt = (ws_size >= off);   // fall back to f32 gemm if slot doesn't fit

    (void)hipFuncSetAttribute((const void*)gru_layer,
                              hipFuncAttributeMaxDynamicSharedMemorySize, 99072);

    (void)hipMemsetAsync(ctrl, 0, 3 * 16384, stream);
    embed_kernel<<<dim3(8192), dim3(256), 0, stream>>>(x, emb, seq0);

    const f16* lin = seq0; int lda = 256, K = 256;
    f16* ybufs[2] = {ybuf0, ybuf1};
    for (int l = 0; l < 3; ++l) {
        const float* Wg_fw = (const float*)d_in[4 + l * 10 + 0];
        const float* bg_fw = (const float*)d_in[4 + l * 10 + 1];
        const float* Wc_fw = (const float*)d_in[4 + l * 10 + 2];
        const float* bc_fw = (const float*)d_in[4 + l * 10 + 3];
        const float* h0_fw = (const float*)d_in[4 + l * 10 + 4];
        const float* Wg_bw = (const float*)d_in[4 + l * 10 + 5];
        const float* bg_bw = (const float*)d_in[4 + l * 10 + 6];
        const float* Wc_bw = (const float*)d_in[4 + l * 10 + 7];
        const float* bc_bw = (const float*)d_in[4 + l * 10 + 8];
        const float* h0_bw = (const float*)d_in[4 + l * 10 + 9];
        int din = (l == 0) ? 256 : 2048;
        int K2 = din + 1024;

        if (cvt) {
            wconv<<<dim3(K2 / 32, 64, 2), dim3(256), 0, stream>>>(Wg_fw, Wc_fw, WgT_fw, WcT_fw, K2);
            wconv<<<dim3(K2 / 32, 64, 2), dim3(256), 0, stream>>>(Wg_bw, Wc_bw, WgT_bw, WcT_bw, K2);
            gemm_projT<<<dim3(64, 24), dim3(256), 0, stream>>>(lin, lda, K, WgT_fw, WcT_fw, K2, bg_fw, bc_fw, projfw);
            gemm_projT<<<dim3(64, 24), dim3(256), 0, stream>>>(lin, lda, K, WgT_bw, WcT_bw, K2, bg_bw, bc_bw, projbw);
        } else {
            gemm_proj<<<dim3(64, 24), dim3(256), 0, stream>>>(lin, lda, K, Wg_fw, Wc_fw, bg_fw, bc_fw, projfw);
            gemm_proj<<<dim3(64, 24), dim3(256), 0, stream>>>(lin, lda, K, Wg_bw, Wc_bw, bg_bw, bc_bw, projbw);
        }

        const float* Wgh_fw = Wg_fw + (size_t)din * 2048;
        const float* Wgh_bw = Wg_bw + (size_t)din * 2048;
        const float* Wch_fw = Wc_fw + (size_t)din * 1024;
        const float* Wch_bw = Wc_bw + (size_t)din * 1024;
        f16* yout = ybufs[l & 1];
        float* stfw = out + 1048576 + l * 32768;
        float* stbw = out + 1048576 + 98304 + l * 32768;
        unsigned* cnt = ctrl + l * 4096;

        gru_layer<<<dim3(128), dim3(256), 99072, stream>>>(
            projfw, projbw, Wgh_fw, Wgh_bw, Wch_fw, Wch_bw, h0_fw, h0_bw,
            h16, rh16, u32, yout, stfw, stbw, cnt);
        lin = yout; lda = 2048; K = 2048;
    }

    gemm_fc<<<dim3(64), dim3(256), 0, stream>>>(ybufs[0], fcW, fcb, out);
}